// Round 1
// baseline (1105.277 us; speedup 1.0000x reference)
//
#include <hip/hip_runtime.h>
#include <hip/hip_bf16.h>

// Problem constants (from reference)
#define BB 8192
#define KK 16
#define VV 50000
#define DD 64
#define CRR 8
#define NRR 64
#define CCC 16
#define NCC 128
#define OUTN 32
#define NROOT 200000
#define NCHILD 500000

// ws float-layout:
//  [0,64)    rsum       [64,128) rsumsq
//  [128,256) csum       [256,384) csumsq
//  [384,448) a_r        [448,512) b_r
//  [512,544) c0
//  [576,4672) WpT[o][n] (32 x 128)
//  byte 18688: P as bf16 [16][50000][32]  (51.2 MB)
#define WS_P_BYTE_OFF 18688

__global__ __launch_bounds__(256) void stats_root_k(const int* __restrict__ idx,
                                                    const float* __restrict__ root_num,
                                                    float* __restrict__ ws) {
    int t = threadIdx.x;
    int col = t & 63;
    int rs = t >> 6; // 0..3
    float s = 0.f, ss = 0.f;
    for (int r = blockIdx.x * 4 + rs; r < BB; r += 64 * 4) {
        int id = idx[r];
        float v = root_num[id * NRR + col];
        s += v; ss += v * v;
    }
    atomicAdd(&ws[col], s);
    atomicAdd(&ws[64 + col], ss);
}

__global__ __launch_bounds__(256) void stats_child_k(const int* __restrict__ cfi,
                                                     const float* __restrict__ child_num,
                                                     float* __restrict__ ws) {
    int t = threadIdx.x;
    int col = t & 127;
    int rs = t >> 7; // 0..1
    float s = 0.f, ss = 0.f;
    for (int r = blockIdx.x * 2 + rs; r < BB * KK; r += 256 * 2) {
        int cf = cfi[r];
        float v = child_num[cf * NCC + col];
        s += v; ss += v * v;
    }
    atomicAdd(&ws[128 + col], s);
    atomicAdd(&ws[256 + col], ss);
}

__global__ __launch_bounds__(256) void finalize_k(float* __restrict__ ws,
                                                  const float* __restrict__ W,
                                                  const float* __restrict__ bvec,
                                                  const float* __restrict__ gr,
                                                  const float* __restrict__ brr,
                                                  const float* __restrict__ gc,
                                                  const float* __restrict__ bcc) {
    __shared__ float sa[NCC], sb[NCC];
    int t = threadIdx.x;
    if (t < NRR) {
        float mu = ws[t] * (1.f / BB);
        float var = ws[64 + t] * (1.f / BB) - mu * mu;
        float a = gr[t] * rsqrtf(fmaxf(var, 0.f) + 1e-5f);
        ws[384 + t] = a;
        ws[448 + t] = brr[t] - mu * a;
    }
    if (t < NCC) {
        float mu = ws[128 + t] * (1.f / (BB * KK));
        float var = ws[256 + t] * (1.f / (BB * KK)) - mu * mu;
        float a = gc[t] * rsqrtf(fmaxf(var, 0.f) + 1e-5f);
        sa[t] = a;
        sb[t] = bcc[t] - mu * a;
    }
    __syncthreads();
    // WpT[o][n] = a_n * W[o][1024+n]
    for (int i = t; i < OUTN * NCC; i += 256) {
        int o = i >> 7, n = i & 127;
        ws[576 + i] = sa[n] * W[o * 1152 + 1024 + n];
    }
    if (t < OUTN) {
        float acc = bvec[t];
        for (int n = 0; n < NCC; n++) acc += sb[n] * W[t * 1152 + 1024 + n];
        ws[512 + t] = acc;
    }
}

// P[c][v][o] = sum_d emb_child[c][v][d] * W[o][c*64+d], stored bf16
__global__ __launch_bounds__(256) void p_precompute_k(const float* __restrict__ emb_child,
                                                      const float* __restrict__ W,
                                                      __hip_bfloat16* __restrict__ P) {
    int t = threadIdx.x;
    int o = t & 31;
    int vs = t >> 5; // 0..7
    int c = blockIdx.y;
    float w[64];
    const float4* Wrow = (const float4*)(W + o * 1152 + c * 64);
#pragma unroll
    for (int i = 0; i < 16; i++) {
        float4 f = Wrow[i];
        w[i * 4 + 0] = f.x; w[i * 4 + 1] = f.y; w[i * 4 + 2] = f.z; w[i * 4 + 3] = f.w;
    }
    for (int v = blockIdx.x * 8 + vs; v < VV; v += gridDim.x * 8) {
        const float4* e = (const float4*)(emb_child + ((size_t)(c * VV + v)) * DD);
        float a0 = 0.f, a1 = 0.f, a2 = 0.f, a3 = 0.f;
#pragma unroll
        for (int i = 0; i < 16; i++) {
            float4 x = e[i];
            a0 += x.x * w[i * 4 + 0];
            a1 += x.y * w[i * 4 + 1];
            a2 += x.z * w[i * 4 + 2];
            a3 += x.w * w[i * 4 + 3];
        }
        P[((size_t)(c * VV + v)) * OUTN + o] = __float2bfloat16((a0 + a1) + (a2 + a3));
    }
}

__global__ __launch_bounds__(256) void root_k(const int* __restrict__ idx,
                                              const int* __restrict__ root_cat,
                                              const float* __restrict__ root_num,
                                              const float* __restrict__ emb_root,
                                              const float* __restrict__ ws,
                                              float* __restrict__ out) {
    int t = threadIdx.x;
    int lane = t & 63;
    int i = blockIdx.x * 4 + (t >> 6);
    int id = idx[i];
    float* orow = out + (size_t)i * 608;
    const int* rc = root_cat + id * CRR;
#pragma unroll
    for (int c = 0; c < CRR; c++) {
        int v = rc[c];
        orow[c * 64 + lane] = emb_root[((size_t)(c * VV + v)) * DD + lane];
    }
    float x = root_num[id * NRR + lane];
    orow[512 + lane] = x * ws[384 + lane] + ws[448 + lane];
}

// half-wave (32 lanes, lane=o) per parent; 16 children sequential; W' in regs
__global__ __launch_bounds__(256, 2) void child_k(const int* __restrict__ cfi,
                                                  const int* __restrict__ child_cat,
                                                  const float* __restrict__ child_num,
                                                  const float* __restrict__ ws,
                                                  const __hip_bfloat16* __restrict__ P,
                                                  float* __restrict__ out) {
    int t = threadIdx.x;
    int lane = t & 63;
    int o = lane & 31;
    int p = blockIdx.x * 8 + (t >> 5); // parent index, 8 half-waves per block

    // stage W' column (for this o) into 128 VGPRs
    float wreg[NCC];
    const float4* wp4 = (const float4*)(ws + 576 + o * NCC);
#pragma unroll
    for (int i = 0; i < 32; i++) {
        float4 f = wp4[i];
        wreg[i * 4 + 0] = f.x; wreg[i * 4 + 1] = f.y; wreg[i * 4 + 2] = f.z; wreg[i * 4 + 3] = f.w;
    }
    float c0 = ws[512 + o];

    float hsum = 0.f;
#pragma unroll 1
    for (int k = 0; k < KK; k++) {
        int j = p * KK + k;
        int cf = cfi[j];
        float a0 = c0, a1 = 0.f, a2 = 0.f, a3 = 0.f;
        // cat part: 16 bf16 P-gathers
        const int4* ccat = (const int4*)(child_cat + cf * CCC);
#pragma unroll
        for (int c4 = 0; c4 < 4; c4++) {
            int4 vv = ccat[c4];
            a0 += __bfloat162float(P[((size_t)((c4 * 4 + 0) * VV + vv.x)) * OUTN + o]);
            a1 += __bfloat162float(P[((size_t)((c4 * 4 + 1) * VV + vv.y)) * OUTN + o]);
            a2 += __bfloat162float(P[((size_t)((c4 * 4 + 2) * VV + vv.z)) * OUTN + o]);
            a3 += __bfloat162float(P[((size_t)((c4 * 4 + 3) * VV + vv.w)) * OUTN + o]);
        }
        // num part: 128-wide dot with W' (registers), x broadcast per half-wave
        const float4* xrow = (const float4*)(child_num + cf * NCC);
#pragma unroll
        for (int n4 = 0; n4 < 32; n4++) {
            float4 x = xrow[n4];
            a0 += x.x * wreg[n4 * 4 + 0];
            a1 += x.y * wreg[n4 * 4 + 1];
            a2 += x.z * wreg[n4 * 4 + 2];
            a3 += x.w * wreg[n4 * 4 + 3];
        }
        hsum += fmaxf((a0 + a1) + (a2 + a3), 0.f);
    }
    out[(size_t)p * 608 + 576 + o] = hsum * (1.f / 16.f);
}

extern "C" void kernel_launch(void* const* d_in, const int* in_sizes, int n_in,
                              void* d_out, int out_size, void* d_ws, size_t ws_size,
                              hipStream_t stream) {
    const int* idx       = (const int*)d_in[0];
    const int* cfi       = (const int*)d_in[1];
    const int* root_cat  = (const int*)d_in[2];
    const int* child_cat = (const int*)d_in[3];
    const float* root_num  = (const float*)d_in[4];
    const float* child_num = (const float*)d_in[5];
    const float* emb_root  = (const float*)d_in[6];
    const float* emb_child = (const float*)d_in[7];
    const float* W     = (const float*)d_in[8];
    const float* bvec  = (const float*)d_in[9];
    const float* gr    = (const float*)d_in[10];
    const float* brr   = (const float*)d_in[11];
    const float* gc    = (const float*)d_in[12];
    const float* bcc   = (const float*)d_in[13];

    float* out = (float*)d_out;
    float* wsf = (float*)d_ws;
    __hip_bfloat16* P = (__hip_bfloat16*)((char*)d_ws + WS_P_BYTE_OFF);

    // zero the atomic-stats region
    hipMemsetAsync(d_ws, 0, 1536, stream);

    stats_root_k<<<64, 256, 0, stream>>>(idx, root_num, wsf);
    stats_child_k<<<256, 256, 0, stream>>>(cfi, child_num, wsf);
    finalize_k<<<1, 256, 0, stream>>>(wsf, W, bvec, gr, brr, gc, bcc);
    p_precompute_k<<<dim3(128, 16), 256, 0, stream>>>(emb_child, W, P);
    root_k<<<BB / 4, 256, 0, stream>>>(idx, root_cat, root_num, emb_root, wsf, out);
    child_k<<<BB / 8, 256, 0, stream>>>(cfi, child_cat, child_num, wsf, P, out);
}